// Round 1
// baseline (209.083 us; speedup 1.0000x reference)
//
#include <hip/hip_runtime.h>

// LoRA: out = x @ (A@B) * 1.0, computed as (x@A)@B.
// x: [M=16384, K=4096] f32, A: [K, 16] f32, B: [16, N=4096] f32.
constexpr int RANK = 16;
constexpr int K = 4096;
constexpr int N = 4096;
constexpr int M = 4 * 4096;
constexpr int ROWS2 = 32;  // rows per block in kernel 2

// ---------------- Kernel 1: T = x @ A ----------------
// One wave per 4 rows. Lane l covers k = it*256 + 4l .. +3 (float4, coalesced).
// acc: 4 rows x 16 rank = vals[64], statically indexed.
// End: recursive-halving reduce-scatter (63 shuffles) -> lane i holds
// element i of the 64-float tile -> one coalesced 256B store per wave.

#define ACC_ROW(R, XS)                                      \
  vals[(R)*16 + 0]  = fmaf((XS), a0.x, vals[(R)*16 + 0]);   \
  vals[(R)*16 + 1]  = fmaf((XS), a0.y, vals[(R)*16 + 1]);   \
  vals[(R)*16 + 2]  = fmaf((XS), a0.z, vals[(R)*16 + 2]);   \
  vals[(R)*16 + 3]  = fmaf((XS), a0.w, vals[(R)*16 + 3]);   \
  vals[(R)*16 + 4]  = fmaf((XS), a1.x, vals[(R)*16 + 4]);   \
  vals[(R)*16 + 5]  = fmaf((XS), a1.y, vals[(R)*16 + 5]);   \
  vals[(R)*16 + 6]  = fmaf((XS), a1.z, vals[(R)*16 + 6]);   \
  vals[(R)*16 + 7]  = fmaf((XS), a1.w, vals[(R)*16 + 7]);   \
  vals[(R)*16 + 8]  = fmaf((XS), a2.x, vals[(R)*16 + 8]);   \
  vals[(R)*16 + 9]  = fmaf((XS), a2.y, vals[(R)*16 + 9]);   \
  vals[(R)*16 + 10] = fmaf((XS), a2.z, vals[(R)*16 + 10]);  \
  vals[(R)*16 + 11] = fmaf((XS), a2.w, vals[(R)*16 + 11]);  \
  vals[(R)*16 + 12] = fmaf((XS), a3.x, vals[(R)*16 + 12]);  \
  vals[(R)*16 + 13] = fmaf((XS), a3.y, vals[(R)*16 + 13]);  \
  vals[(R)*16 + 14] = fmaf((XS), a3.z, vals[(R)*16 + 14]);  \
  vals[(R)*16 + 15] = fmaf((XS), a3.w, vals[(R)*16 + 15]);

__global__ __launch_bounds__(256) void lora_xa(const float* __restrict__ x,
                                               const float* __restrict__ A,
                                               float* __restrict__ T) {
  const int lane = threadIdx.x & 63;
  const int wave = threadIdx.x >> 6;
  const int r0 = blockIdx.x * 16 + wave * 4;  // this wave's 4 rows

  const float4* __restrict__ x4 = reinterpret_cast<const float4*>(x);
  const float4* __restrict__ A4 = reinterpret_cast<const float4*>(A);

  float vals[64];
#pragma unroll
  for (int i = 0; i < 64; ++i) vals[i] = 0.0f;

  for (int it = 0; it < 16; ++it) {
    const int kb = it * 256 + lane * 4;
    const float4 xv0 = x4[((size_t)(r0 + 0) * K + kb) >> 2];
    const float4 xv1 = x4[((size_t)(r0 + 1) * K + kb) >> 2];
    const float4 xv2 = x4[((size_t)(r0 + 2) * K + kb) >> 2];
    const float4 xv3 = x4[((size_t)(r0 + 3) * K + kb) >> 2];
#pragma unroll
    for (int i = 0; i < 4; ++i) {
      const int k = kb + i;
      const float4 a0 = A4[k * 4 + 0];
      const float4 a1 = A4[k * 4 + 1];
      const float4 a2 = A4[k * 4 + 2];
      const float4 a3 = A4[k * 4 + 3];
      const float xs0 = (i == 0) ? xv0.x : (i == 1) ? xv0.y : (i == 2) ? xv0.z : xv0.w;
      const float xs1 = (i == 0) ? xv1.x : (i == 1) ? xv1.y : (i == 2) ? xv1.z : xv1.w;
      const float xs2 = (i == 0) ? xv2.x : (i == 1) ? xv2.y : (i == 2) ? xv2.z : xv2.w;
      const float xs3 = (i == 0) ? xv3.x : (i == 1) ? xv3.y : (i == 2) ? xv3.z : xv3.w;
      ACC_ROW(0, xs0)
      ACC_ROW(1, xs1)
      ACC_ROW(2, xs2)
      ACC_ROW(3, xs3)
    }
  }

  // Recursive-halving reduce-scatter across the 64 lanes.
  // After all steps, lane i holds the fully-summed element i (r=i>>4, j=i&15).
#define RSTEP(HALF)                                            \
  {                                                            \
    const bool hi = (lane & (HALF)) != 0;                      \
    _Pragma("unroll")                                          \
    for (int i = 0; i < (HALF); ++i) {                         \
      const float send = hi ? vals[i] : vals[i + (HALF)];      \
      const float keep = hi ? vals[i + (HALF)] : vals[i];      \
      vals[i] = keep + __shfl_xor(send, (HALF), 64);           \
    }                                                          \
  }
  RSTEP(32)
  RSTEP(16)
  RSTEP(8)
  RSTEP(4)
  RSTEP(2)
  RSTEP(1)
#undef RSTEP

  T[(size_t)(r0 + (lane >> 4)) * RANK + (lane & 15)] = vals[0];
}

// ---------------- Kernel 2: out = T @ B ----------------
// Each thread holds B[0..15][n0..n0+3] in 64 VGPRs (loaded once), then loops
// ROWS2 rows. T reads are wave-uniform (scalar path); stores are coalesced
// float4 at 16B/lane.
__global__ __launch_bounds__(256) void lora_tb(const float* __restrict__ T,
                                               const float* __restrict__ B,
                                               float* __restrict__ out) {
  const int n0 = blockIdx.x * 1024 + threadIdx.x * 4;
  const int r0 = blockIdx.y * ROWS2;

  const float4* __restrict__ B4 = reinterpret_cast<const float4*>(B);
  float4* __restrict__ out4 = reinterpret_cast<float4*>(out);

  float4 b[16];
#pragma unroll
  for (int j = 0; j < RANK; ++j) b[j] = B4[((size_t)j * N + n0) >> 2];

  for (int r = 0; r < ROWS2; ++r) {
    const float* __restrict__ t = T + (size_t)(r0 + r) * RANK;
    float4 acc;
    acc.x = acc.y = acc.z = acc.w = 0.0f;
#pragma unroll
    for (int j = 0; j < RANK; ++j) {
      const float ts = t[j];
      acc.x = fmaf(ts, b[j].x, acc.x);
      acc.y = fmaf(ts, b[j].y, acc.y);
      acc.z = fmaf(ts, b[j].z, acc.z);
      acc.w = fmaf(ts, b[j].w, acc.w);
    }
    out4[((size_t)(r0 + r) * N + n0) >> 2] = acc;
  }
}

extern "C" void kernel_launch(void* const* d_in, const int* in_sizes, int n_in,
                              void* d_out, int out_size, void* d_ws, size_t ws_size,
                              hipStream_t stream) {
  const float* x = (const float*)d_in[0];   // [M, K]
  const float* A = (const float*)d_in[1];   // [K, RANK]
  const float* B = (const float*)d_in[2];   // [RANK, N]
  float* out = (float*)d_out;               // [M, N]
  float* T = (float*)d_ws;                  // [M, RANK] scratch (1 MiB)

  // Kernel 1: 16 rows per block (4 waves x 4 rows) -> 1024 blocks.
  lora_xa<<<M / 16, 256, 0, stream>>>(x, A, T);

  // Kernel 2: grid (N/1024, M/ROWS2).
  lora_tb<<<dim3(N / 1024, M / ROWS2), 256, 0, stream>>>(T, B, out);
}

// Round 2
// 133.236 us; speedup vs baseline: 1.5693x; 1.5693x over previous
//
#include <hip/hip_runtime.h>

// LoRA: out = x @ (A@B) * 1.0, computed as (x@A)@B.
// x: [M=16384, K=4096] f32, A: [K, 16] f32, B: [16, N=4096] f32.
constexpr int RANK = 16;
constexpr int K = 4096;
constexpr int N = 4096;
constexpr int M = 4 * 4096;
constexpr int KC = 512;       // K-chunk staged in LDS (512 rows x 64B = 32KB)
constexpr int NCHUNK = K / KC;
constexpr int ROWS2 = 32;     // rows per block in kernel 2

// ---------------- Kernel 1: T = x @ A ----------------
// Block = 256 threads (4 waves), 16 rows (4 per wave). Loop over 8 K-chunks:
//   stage A[c*512 .. +512][0..15] into LDS (coalesced float4, slot-XOR
//   swizzled), then 8 k-blocks of 64 k's (one k per lane, stride-1 ->
//   coalesced 256B x dword loads + conflict-free ds_read_b128 of A rows).
// Epilogue: recursive-halving reduce-scatter (63 shuffles) -> lane i holds
// element i of the 64-float tile -> one coalesced 256B store per wave.
//
// LDS swizzle: slot s (floats 4s..4s+3) of row k stored at position
// p = s ^ ((k>>2)&3). Reader lane l (row k = kb+l, m=(l>>2)&3) reads
// position s^m to get true slot s (lane-uniform j!), with byte phases
// spanning all 8 16B-slots per 128B bank period (bits l0,l2,l3) ->
// conflict-free 8-phase wave64 ds_read_b128.

__global__ __launch_bounds__(256) void lora_xa(const float* __restrict__ x,
                                               const float* __restrict__ A,
                                               float* __restrict__ T) {
  const int lane = threadIdx.x & 63;
  const int tid = threadIdx.x;
  const int wave = tid >> 6;
  const int r0 = blockIdx.x * 16 + wave * 4;  // this wave's 4 rows
  const int m = (lane >> 2) & 3;

  __shared__ float4 As[KC * 4];  // 32 KB, swizzled slots

  const float4* __restrict__ A4 = reinterpret_cast<const float4*>(A);

  float vals[64];
#pragma unroll
  for (int i = 0; i < 64; ++i) vals[i] = 0.0f;

  for (int c = 0; c < NCHUNK; ++c) {
    // ---- stage chunk c: KC*4 = 2048 float4 slots, 8 per thread ----
    __syncthreads();  // protect LDS from previous chunk's readers
#pragma unroll
    for (int q = 0; q < 8; ++q) {
      const int n = q * 256 + tid;              // slot index 0..2047
      const int k = n >> 2;                     // local row
      const int s = n & 3;                      // true slot
      const int p = s ^ ((k >> 2) & 3);         // swizzled position
      As[k * 4 + p] = A4[(size_t)(c * KC + k) * 4 + s];
    }
    __syncthreads();

    // ---- compute: 8 k-blocks of 64 (one k per lane) ----
#pragma unroll
    for (int kbi = 0; kbi < 8; ++kbi) {
      const int kl = kbi * 64 + lane;           // local k in chunk
      const size_t kg = (size_t)c * KC + kl;    // global k

      float xv[4];
#pragma unroll
      for (int r = 0; r < 4; ++r) xv[r] = x[(size_t)(r0 + r) * K + kg];

      float4 a[4];
#pragma unroll
      for (int s = 0; s < 4; ++s) a[s] = As[kl * 4 + (s ^ m)];

#pragma unroll
      for (int r = 0; r < 4; ++r) {
#pragma unroll
        for (int s = 0; s < 4; ++s) {
          vals[r * 16 + 4 * s + 0] = fmaf(xv[r], a[s].x, vals[r * 16 + 4 * s + 0]);
          vals[r * 16 + 4 * s + 1] = fmaf(xv[r], a[s].y, vals[r * 16 + 4 * s + 1]);
          vals[r * 16 + 4 * s + 2] = fmaf(xv[r], a[s].z, vals[r * 16 + 4 * s + 2]);
          vals[r * 16 + 4 * s + 3] = fmaf(xv[r], a[s].w, vals[r * 16 + 4 * s + 3]);
        }
      }
    }
  }

  // Recursive-halving reduce-scatter across the 64 lanes.
  // After all steps, lane i holds the fully-summed element i (r=i>>4, j=i&15).
#define RSTEP(HALF)                                            \
  {                                                            \
    const bool hi = (lane & (HALF)) != 0;                      \
    _Pragma("unroll")                                          \
    for (int i = 0; i < (HALF); ++i) {                         \
      const float send = hi ? vals[i] : vals[i + (HALF)];      \
      const float keep = hi ? vals[i + (HALF)] : vals[i];      \
      vals[i] = keep + __shfl_xor(send, (HALF), 64);           \
    }                                                          \
  }
  RSTEP(32)
  RSTEP(16)
  RSTEP(8)
  RSTEP(4)
  RSTEP(2)
  RSTEP(1)
#undef RSTEP

  T[(size_t)(r0 + (lane >> 4)) * RANK + (lane & 15)] = vals[0];
}

// ---------------- Kernel 2: out = T @ B ----------------
// Each thread holds B[0..15][n0..n0+3] in 64 VGPRs (loaded once), then loops
// ROWS2 rows. T reads are wave-uniform (scalar path); stores are coalesced
// float4 at 16B/lane.
__global__ __launch_bounds__(256) void lora_tb(const float* __restrict__ T,
                                               const float* __restrict__ B,
                                               float* __restrict__ out) {
  const int n0 = blockIdx.x * 1024 + threadIdx.x * 4;
  const int r0 = blockIdx.y * ROWS2;

  const float4* __restrict__ B4 = reinterpret_cast<const float4*>(B);
  float4* __restrict__ out4 = reinterpret_cast<float4*>(out);

  float4 b[16];
#pragma unroll
  for (int j = 0; j < RANK; ++j) b[j] = B4[((size_t)j * N + n0) >> 2];

  for (int r = 0; r < ROWS2; ++r) {
    const float* __restrict__ t = T + (size_t)(r0 + r) * RANK;
    float4 acc;
    acc.x = acc.y = acc.z = acc.w = 0.0f;
#pragma unroll
    for (int j = 0; j < RANK; ++j) {
      const float ts = t[j];
      acc.x = fmaf(ts, b[j].x, acc.x);
      acc.y = fmaf(ts, b[j].y, acc.y);
      acc.z = fmaf(ts, b[j].z, acc.z);
      acc.w = fmaf(ts, b[j].w, acc.w);
    }
    out4[((size_t)(r0 + r) * N + n0) >> 2] = acc;
  }
}

extern "C" void kernel_launch(void* const* d_in, const int* in_sizes, int n_in,
                              void* d_out, int out_size, void* d_ws, size_t ws_size,
                              hipStream_t stream) {
  const float* x = (const float*)d_in[0];   // [M, K]
  const float* A = (const float*)d_in[1];   // [K, RANK]
  const float* B = (const float*)d_in[2];   // [RANK, N]
  float* out = (float*)d_out;               // [M, N]
  float* T = (float*)d_ws;                  // [M, RANK] scratch (1 MiB)

  // Kernel 1: 16 rows per block (4 waves x 4 rows) -> 1024 blocks.
  lora_xa<<<M / 16, 256, 0, stream>>>(x, A, T);

  // Kernel 2: grid (N/1024, M/ROWS2).
  lora_tb<<<dim3(N / 1024, M / ROWS2), 256, 0, stream>>>(T, B, out);
}